// Round 1
// baseline (3112.287 us; speedup 1.0000x reference)
//
#include <hip/hip_runtime.h>
#include <math.h>

#define K_IN 12288
#define HID  1024
#define G4   4096
#define TS   256

// ---------------------------------------------------------------------------
// Kernel 1: x_proj[t][j] = dot(x[t,:], W_ih[j,:]) + b_ih[j] + b_hh[j]
// fp32 vector GEMM, BM=64 (j) x BN=64 (t) x BK=16, 4x4 micro-tile per thread.
// ---------------------------------------------------------------------------
#define BM 64
#define BN 64
#define BK 16
#define LDP 68   // padded LDS row stride (16B aligned, breaks bank conflicts)

__global__ __launch_bounds__(256) void xproj_gemm(
    const float* __restrict__ X,    // (256, 12288) frames flattened
    const float* __restrict__ W,    // (4096, 12288)
    const float* __restrict__ b_ih, // (4096)
    const float* __restrict__ b_hh, // (4096)
    float* __restrict__ xproj)      // (256, 4096)
{
  __shared__ float As[BK][LDP];  // k-major: As[k][j]
  __shared__ float Bs[BK][LDP];  // k-major: Bs[k][t]
  const int tid = threadIdx.x;
  const int j0 = blockIdx.y * BM;   // y = j-block so concurrent x-blocks share A
  const int t0 = blockIdx.x * BN;
  const int rr = tid >> 2;          // 0..63 row within tile
  const int kq = tid & 3;           // 0..3 k-quad

  float acc[4][4];
#pragma unroll
  for (int a = 0; a < 4; ++a)
#pragma unroll
    for (int b = 0; b < 4; ++b) acc[a][b] = 0.f;

  const int tj = (tid & 15) * 4;    // j micro-offset
  const int ti = (tid >> 4) * 4;    // t micro-offset

  for (int k0 = 0; k0 < K_IN; k0 += BK) {
    float4 av = *(const float4*)(W + (size_t)(j0 + rr) * K_IN + k0 + kq * 4);
    float4 bv = *(const float4*)(X + (size_t)(t0 + rr) * K_IN + k0 + kq * 4);
    __syncthreads();  // protect LDS from previous iteration's readers
    As[kq * 4 + 0][rr] = av.x;
    As[kq * 4 + 1][rr] = av.y;
    As[kq * 4 + 2][rr] = av.z;
    As[kq * 4 + 3][rr] = av.w;
    Bs[kq * 4 + 0][rr] = bv.x;
    Bs[kq * 4 + 1][rr] = bv.y;
    Bs[kq * 4 + 2][rr] = bv.z;
    Bs[kq * 4 + 3][rr] = bv.w;
    __syncthreads();
#pragma unroll
    for (int kk = 0; kk < BK; ++kk) {
      float4 a = *(const float4*)&As[kk][tj];
      float4 b = *(const float4*)&Bs[kk][ti];
      acc[0][0] += a.x * b.x; acc[0][1] += a.x * b.y; acc[0][2] += a.x * b.z; acc[0][3] += a.x * b.w;
      acc[1][0] += a.y * b.x; acc[1][1] += a.y * b.y; acc[1][2] += a.y * b.z; acc[1][3] += a.y * b.w;
      acc[2][0] += a.z * b.x; acc[2][1] += a.z * b.y; acc[2][2] += a.z * b.z; acc[2][3] += a.z * b.w;
      acc[3][0] += a.w * b.x; acc[3][1] += a.w * b.y; acc[3][2] += a.w * b.z; acc[3][3] += a.w * b.w;
    }
  }

  // epilogue: add both biases, store (t,4096) layout, coalesced float4
  float bias[4];
#pragma unroll
  for (int x = 0; x < 4; ++x) bias[x] = b_ih[j0 + tj + x] + b_hh[j0 + tj + x];
#pragma unroll
  for (int y = 0; y < 4; ++y) {
    const int t = t0 + ti + y;
    float4 o;
    o.x = acc[0][y] + bias[0];
    o.y = acc[1][y] + bias[1];
    o.z = acc[2][y] + bias[2];
    o.w = acc[3][y] + bias[3];
    *(float4*)(xproj + (size_t)t * G4 + j0 + tj) = o;
  }
}

// ---------------------------------------------------------------------------
// Kernel 2: persistent LSTM scan. 128 WGs x 256 threads, one per CU.
// WG w owns hidden units [w*8, w*8+8): 32 W_hh rows (4 gates x 8 units),
// held entirely in registers (128 VGPRs/thread). h broadcast via global
// double-buffer + per-WG step-tagged flags (device-scope atomics).
// Flags start as 0xAAAAAAAA poison = negative int -> readers spin until real.
// ---------------------------------------------------------------------------
#define NWG 128
#define UPW 8

__global__ __launch_bounds__(256, 1) void lstm_scan(
    const float* __restrict__ W_hh,   // (4096, 1024)
    const float* __restrict__ xproj,  // (256, 4096)
    float* __restrict__ hbuf,         // (2, 1024)
    int* __restrict__ flags)          // NWG entries, 64B apart
{
  const int tid = threadIdx.x;
  const int w = blockIdx.x;
  const int u0 = w * UPW;
  const int r = tid >> 3;            // 0..31 local row; wave g handles gate g
  const int sub = tid & 7;           // 8 lanes per row, 128 elems each
  const int gate = r >> 3;           // 0..3
  const int uu = r & 7;              // 0..7
  const int hrow = gate * HID + u0 + uu;  // row in W_hh == index into gates vec

  __shared__ __align__(16) float h_lds[8 * 132];  // sub-major, stride 132 (bank-safe)
  __shared__ float gates_lds[32];
  __shared__ float c_lds[UPW];

  // load my 128-float W_hh segment into registers
  float4 Wreg[32];
  const float4* wp = (const float4*)(W_hh + (size_t)hrow * HID + sub * 128);
#pragma unroll
  for (int i = 0; i < 32; ++i) Wreg[i] = wp[i];

  if (tid < UPW) c_lds[tid] = 0.f;
  __syncthreads();

  for (int t = 0; t < TS; ++t) {
    float partial = 0.f;
    if (t > 0) {
      // wait for all WGs to have published h_t
      if (tid < NWG) {
        while (__hip_atomic_load(&flags[tid * 16], __ATOMIC_ACQUIRE,
                                 __HIP_MEMORY_SCOPE_AGENT) < t) { }
      }
      __syncthreads();
      // read h_t (device-scope loads bypass stale L1), stage into LDS strided
      const float* hb = hbuf + (t & 1) * HID;
      const int kbase = tid * 4;
      float hv[4];
#pragma unroll
      for (int d = 0; d < 4; ++d)
        hv[d] = __hip_atomic_load(&hb[kbase + d], __ATOMIC_RELAXED,
                                  __HIP_MEMORY_SCOPE_AGENT);
      const int st = tid >> 5;           // which 128-chunk
      const int off = (tid & 31) * 4;
#pragma unroll
      for (int d = 0; d < 4; ++d) h_lds[st * 132 + off + d] = hv[d];
      __syncthreads();
      // dot: my row segment x my h segment (conflict-free, broadcast reads)
      const float4* hl = (const float4*)(h_lds + sub * 132);
#pragma unroll
      for (int i = 0; i < 32; ++i) {
        float4 h4 = hl[i];
        partial += Wreg[i].x * h4.x + Wreg[i].y * h4.y +
                   Wreg[i].z * h4.z + Wreg[i].w * h4.w;
      }
    }
    // reduce across the 8 sub-lanes of this row (same wave)
    partial += __shfl_xor(partial, 1, 64);
    partial += __shfl_xor(partial, 2, 64);
    partial += __shfl_xor(partial, 4, 64);
    if (sub == 0) {
      float gsum = partial + xproj[(size_t)t * G4 + hrow];
      float act = (gate == 2) ? tanhf(gsum) : 1.f / (1.f + expf(-gsum));
      gates_lds[gate * 8 + uu] = act;
    }
    __syncthreads();
    if (tid < UPW) {
      float iv = gates_lds[0 * 8 + tid];
      float fv = gates_lds[1 * 8 + tid];
      float gv = gates_lds[2 * 8 + tid];
      float ov = gates_lds[3 * 8 + tid];
      float c = fv * c_lds[tid] + iv * gv;
      c_lds[tid] = c;
      float hnew = ov * tanhf(c);
      __hip_atomic_store(&hbuf[((t + 1) & 1) * HID + u0 + tid], hnew,
                         __ATOMIC_RELAXED, __HIP_MEMORY_SCOPE_AGENT);
    }
    __syncthreads();  // waits vmcnt(0): h stores complete before flag
    if (tid == 0)
      __hip_atomic_store(&flags[w * 16], t + 1, __ATOMIC_RELEASE,
                         __HIP_MEMORY_SCOPE_AGENT);
  }
}

// ---------------------------------------------------------------------------
// Kernel 3: out[j] = dot(fc_w[j,:], h_T) + fc_b[j].  h_T is in hbuf[0]
// (step 256 is even). 192 WGs x 256 threads, 64 rows/WG, 4 lanes/row.
// ---------------------------------------------------------------------------
__global__ __launch_bounds__(256) void fc_kernel(
    const float* __restrict__ fc_w,  // (12288, 1024)
    const float* __restrict__ fc_b,  // (12288)
    const float* __restrict__ hbuf,  // h_T at hbuf[0..1023]
    float* __restrict__ out)         // (12288)
{
  __shared__ float h_s[HID];
  const int tid = threadIdx.x;
  for (int k = tid; k < HID; k += 256) h_s[k] = hbuf[k];
  __syncthreads();
  const int r = tid >> 2;    // 0..63
  const int sub = tid & 3;   // 0..3, 256 elems each
  const int j = blockIdx.x * 64 + r;
  const float4* wrow = (const float4*)(fc_w + (size_t)j * HID + sub * 256);
  const float4* hp = (const float4*)(h_s + sub * 256);
  float s = 0.f;
#pragma unroll
  for (int i = 0; i < 64; ++i) {
    float4 wv = wrow[i];
    float4 hv = hp[i];
    s += wv.x * hv.x + wv.y * hv.y + wv.z * hv.z + wv.w * hv.w;
  }
  s += __shfl_xor(s, 1, 64);
  s += __shfl_xor(s, 2, 64);
  if (sub == 0) out[j] = s + fc_b[j];
}

// ---------------------------------------------------------------------------
extern "C" void kernel_launch(void* const* d_in, const int* in_sizes, int n_in,
                              void* d_out, int out_size, void* d_ws, size_t ws_size,
                              hipStream_t stream) {
  const float* frames = (const float*)d_in[0];  // (256,3,64,64)
  const float* W_ih   = (const float*)d_in[1];  // (4096,12288)
  const float* W_hh   = (const float*)d_in[2];  // (4096,1024)
  const float* b_ih   = (const float*)d_in[3];  // (4096)
  const float* b_hh   = (const float*)d_in[4];  // (4096)
  const float* fc_w   = (const float*)d_in[5];  // (12288,1024)
  const float* fc_b   = (const float*)d_in[6];  // (12288)
  float* out = (float*)d_out;

  char* ws = (char*)d_ws;
  float* xproj = (float*)ws;                              // 256*4096*4 = 4 MB
  float* hbuf  = (float*)(ws + 4 * 1024 * 1024);          // 2*1024*4 = 8 KB
  int*   flags = (int*)(ws + 4 * 1024 * 1024 + 8192);     // 128*64 B = 8 KB
  // flags deliberately NOT initialized: 0xAA poison reads as negative int,
  // which is < every step tag the protocol waits for.

  xproj_gemm<<<dim3(TS / BN, G4 / BM), 256, 0, stream>>>(frames, W_ih, b_ih, b_hh, xproj);
  lstm_scan<<<dim3(NWG), 256, 0, stream>>>(W_hh, xproj, hbuf, flags);
  fc_kernel<<<dim3(12288 / 64), 256, 0, stream>>>(fc_w, fc_b, hbuf, out);
}

// Round 2
// 1307.624 us; speedup vs baseline: 2.3801x; 2.3801x over previous
//
#include <hip/hip_runtime.h>
#include <math.h>

#define K_IN 12288
#define HID  1024
#define G4   4096
#define TS   256

typedef unsigned long long u64;
typedef unsigned int u32;

// ---------------------------------------------------------------------------
// Kernel 1: partial GEMM  xpart[ks][t][j] = dot(x[t, kspan], W_ih[j, kspan])
// fp32 vector GEMM, BM=64 (j) x BN=64 (t) x BK=16, 4x4 micro-tile per thread.
// K split across blockIdx.z for occupancy (4 blocks/CU -> 16 waves/CU).
// ---------------------------------------------------------------------------
#define BM 64
#define BN 64
#define BK 16
#define LDP 68   // padded LDS row stride

__global__ __launch_bounds__(256) void xproj_gemm(
    const float* __restrict__ X,    // (256, 12288)
    const float* __restrict__ W,    // (4096, 12288)
    float* __restrict__ xpart,      // (nks, 256, 4096)
    int kspan)
{
  __shared__ float As[BK][LDP];  // k-major: As[k][j]
  __shared__ float Bs[BK][LDP];  // k-major: Bs[k][t]
  const int tid = threadIdx.x;
  const int j0 = blockIdx.y * BM;
  const int t0 = blockIdx.x * BN;
  const int ks = blockIdx.z;
  const int kbeg = ks * kspan;
  const int kend = kbeg + kspan;
  const int rr = tid >> 2;          // 0..63 row within tile
  const int kq = tid & 3;           // 0..3 k-quad

  float acc[4][4];
#pragma unroll
  for (int a = 0; a < 4; ++a)
#pragma unroll
    for (int b = 0; b < 4; ++b) acc[a][b] = 0.f;

  const int tj = (tid & 15) * 4;    // j micro-offset
  const int ti = (tid >> 4) * 4;    // t micro-offset

  for (int k0 = kbeg; k0 < kend; k0 += BK) {
    float4 av = *(const float4*)(W + (size_t)(j0 + rr) * K_IN + k0 + kq * 4);
    float4 bv = *(const float4*)(X + (size_t)(t0 + rr) * K_IN + k0 + kq * 4);
    __syncthreads();
    As[kq * 4 + 0][rr] = av.x;
    As[kq * 4 + 1][rr] = av.y;
    As[kq * 4 + 2][rr] = av.z;
    As[kq * 4 + 3][rr] = av.w;
    Bs[kq * 4 + 0][rr] = bv.x;
    Bs[kq * 4 + 1][rr] = bv.y;
    Bs[kq * 4 + 2][rr] = bv.z;
    Bs[kq * 4 + 3][rr] = bv.w;
    __syncthreads();
#pragma unroll
    for (int kk = 0; kk < BK; ++kk) {
      float4 a = *(const float4*)&As[kk][tj];
      float4 b = *(const float4*)&Bs[kk][ti];
      acc[0][0] += a.x * b.x; acc[0][1] += a.x * b.y; acc[0][2] += a.x * b.z; acc[0][3] += a.x * b.w;
      acc[1][0] += a.y * b.x; acc[1][1] += a.y * b.y; acc[1][2] += a.y * b.z; acc[1][3] += a.y * b.w;
      acc[2][0] += a.z * b.x; acc[2][1] += a.z * b.y; acc[2][2] += a.z * b.z; acc[2][3] += a.z * b.w;
      acc[3][0] += a.w * b.x; acc[3][1] += a.w * b.y; acc[3][2] += a.w * b.z; acc[3][3] += a.w * b.w;
    }
  }

  float* outp = xpart + (size_t)ks * TS * G4;
#pragma unroll
  for (int y = 0; y < 4; ++y) {
    const int t = t0 + ti + y;
    float4 o;
    o.x = acc[0][y]; o.y = acc[1][y]; o.z = acc[2][y]; o.w = acc[3][y];
    *(float4*)(outp + (size_t)t * G4 + j0 + tj) = o;
  }
}

// ---------------------------------------------------------------------------
// Kernel 1b: xproj[t][j] = sum_ks xpart[ks][t][j] + b_ih[j] + b_hh[j]
// ---------------------------------------------------------------------------
__global__ __launch_bounds__(256) void xproj_reduce(
    const float* __restrict__ xpart, int nks,
    const float* __restrict__ b_ih, const float* __restrict__ b_hh,
    float* __restrict__ xproj)
{
  const int idx = (blockIdx.x * 256 + threadIdx.x) * 4;  // over TS*G4 elems
  float4 s = *(const float4*)(xpart + idx);
  for (int ks = 1; ks < nks; ++ks) {
    float4 p = *(const float4*)(xpart + (size_t)ks * TS * G4 + idx);
    s.x += p.x; s.y += p.y; s.z += p.z; s.w += p.w;
  }
  const int j = idx & (G4 - 1);
  float4 bi = *(const float4*)(b_ih + j);
  float4 bh = *(const float4*)(b_hh + j);
  s.x += bi.x + bh.x; s.y += bi.y + bh.y; s.z += bi.z + bh.z; s.w += bi.w + bh.w;
  *(float4*)(xproj + idx) = s;
}

// ---------------------------------------------------------------------------
// Kernel 2: persistent LSTM scan. 128 WGs x 256 threads.
// WG w owns hidden units [w*8, w*8+8). W_hh slice in registers (128 VGPR/thr).
// h broadcast: each element published as a packed {tag:u32, val:f32} 8-byte
// RELAXED agent-scope atomic into a double-buffered slot. Consumers spin on
// relaxed 8B loads until the embedded tag == t. No fences, no separate flags:
// value and tag travel in one atom, one visibility hop per step.
// Poisoned ws (0xAAAAAAAA tag) never equals a real tag in [1,256].
// ---------------------------------------------------------------------------
#define NWG 128
#define UPW 8

__global__ __launch_bounds__(256, 1) void lstm_scan(
    const float* __restrict__ W_hh,   // (4096, 1024)
    const float* __restrict__ xproj,  // (256, 4096)
    u64* __restrict__ hmsg)           // (2, 1024) packed {tag,val}
{
  const int tid = threadIdx.x;
  const int w = blockIdx.x;
  const int u0 = w * UPW;
  const int r = tid >> 3;            // 0..31 local row
  const int sub = tid & 7;           // 8 lanes per row, 128 elems each
  const int gate = r >> 3;           // 0..3
  const int uu = r & 7;              // 0..7
  const int hrow = gate * HID + u0 + uu;

  __shared__ __align__(16) float h_lds[8 * 132];
  __shared__ float gates_lds[32];
  __shared__ float c_lds[UPW];

  // my 128-float W_hh segment in registers
  float4 Wreg[32];
  const float4* wp = (const float4*)(W_hh + (size_t)hrow * HID + sub * 128);
#pragma unroll
  for (int i = 0; i < 32; ++i) Wreg[i] = wp[i];

  if (tid < UPW) c_lds[tid] = 0.f;
  __syncthreads();

  for (int t = 0; t < TS; ++t) {
    // prefetch my xproj element early (hides L2/L3 latency behind the spin)
    float xp = 0.f;
    if (sub == 0) xp = xproj[(size_t)t * G4 + hrow];

    float partial = 0.f;
    if (t > 0) {
      // spin until my 4 h elements carry tag == t, extract values
      const u64* slot = hmsg + (t & 1) * HID;
      float hv[4];
#pragma unroll
      for (int d = 0; d < 4; ++d) {
        u64 m;
        do {
          m = __hip_atomic_load(&slot[tid * 4 + d], __ATOMIC_RELAXED,
                                __HIP_MEMORY_SCOPE_AGENT);
        } while ((u32)(m >> 32) != (u32)t);
        hv[d] = __uint_as_float((u32)m);
      }
      __syncthreads();  // B1: prev step's h_lds readers done
      const int st = tid >> 5;
      const int off = (tid & 31) * 4;
#pragma unroll
      for (int d = 0; d < 4; ++d) h_lds[st * 132 + off + d] = hv[d];
      __syncthreads();  // B2: h_lds ready
      const float4* hl = (const float4*)(h_lds + sub * 132);
#pragma unroll
      for (int i = 0; i < 32; ++i) {
        float4 h4 = hl[i];
        partial += Wreg[i].x * h4.x + Wreg[i].y * h4.y +
                   Wreg[i].z * h4.z + Wreg[i].w * h4.w;
      }
    }
    // reduce across the 8 sub-lanes of this row (same wave)
    partial += __shfl_xor(partial, 1, 64);
    partial += __shfl_xor(partial, 2, 64);
    partial += __shfl_xor(partial, 4, 64);
    if (sub == 0) {
      float gsum = partial + xp;
      float act = (gate == 2) ? tanhf(gsum) : 1.f / (1.f + expf(-gsum));
      gates_lds[gate * 8 + uu] = act;
    }
    __syncthreads();  // B3: gates ready
    if (tid < UPW) {
      float iv = gates_lds[0 * 8 + tid];
      float fv = gates_lds[1 * 8 + tid];
      float gv = gates_lds[2 * 8 + tid];
      float ov = gates_lds[3 * 8 + tid];
      float c = fv * c_lds[tid] + iv * gv;
      c_lds[tid] = c;
      float hnew = ov * tanhf(c);
      u64 msg = ((u64)(u32)(t + 1) << 32) | (u64)__float_as_uint(hnew);
      __hip_atomic_store(&hmsg[((t + 1) & 1) * HID + u0 + tid], msg,
                         __ATOMIC_RELAXED, __HIP_MEMORY_SCOPE_AGENT);
    }
    // no trailing barrier needed: B1/B3 of the next iteration protect LDS
  }
}

// ---------------------------------------------------------------------------
// Kernel 3: out[j] = dot(fc_w[j,:], h_T) + fc_b[j].  h_T packed in hmsg slot 0
// (tag 256, step 256 is even) — extract low 32 bits.
// ---------------------------------------------------------------------------
__global__ __launch_bounds__(256) void fc_kernel(
    const float* __restrict__ fc_w,  // (12288, 1024)
    const float* __restrict__ fc_b,  // (12288)
    const u64* __restrict__ hmsg,    // h_T packed at slot 0
    float* __restrict__ out)         // (12288)
{
  __shared__ float h_s[HID];
  const int tid = threadIdx.x;
  for (int k = tid; k < HID; k += 256)
    h_s[k] = __uint_as_float((u32)hmsg[k]);
  __syncthreads();
  const int r = tid >> 2;    // 0..63
  const int sub = tid & 3;   // 256 elems each
  const int j = blockIdx.x * 64 + r;
  const float4* wrow = (const float4*)(fc_w + (size_t)j * HID + sub * 256);
  const float4* hp = (const float4*)(h_s + sub * 256);
  float s = 0.f;
#pragma unroll
  for (int i = 0; i < 64; ++i) {
    float4 wv = wrow[i];
    float4 hv = hp[i];
    s += wv.x * hv.x + wv.y * hv.y + wv.z * hv.z + wv.w * hv.w;
  }
  s += __shfl_xor(s, 1, 64);
  s += __shfl_xor(s, 2, 64);
  if (sub == 0) out[j] = s + fc_b[j];
}

// ---------------------------------------------------------------------------
extern "C" void kernel_launch(void* const* d_in, const int* in_sizes, int n_in,
                              void* d_out, int out_size, void* d_ws, size_t ws_size,
                              hipStream_t stream) {
  const float* frames = (const float*)d_in[0];  // (256,3,64,64)
  const float* W_ih   = (const float*)d_in[1];  // (4096,12288)
  const float* W_hh   = (const float*)d_in[2];  // (4096,1024)
  const float* b_ih   = (const float*)d_in[3];  // (4096)
  const float* b_hh   = (const float*)d_in[4];  // (4096)
  const float* fc_w   = (const float*)d_in[5];  // (12288,1024)
  const float* fc_b   = (const float*)d_in[6];  // (12288)
  float* out = (float*)d_out;

  const size_t XPROJ_BYTES = (size_t)TS * G4 * 4;  // 4 MB
  // pick K-split by available workspace (ws_size is constant across calls)
  int nks = 1;
  if (ws_size >= XPROJ_BYTES * 5 + (1 << 20)) nks = 4;
  else if (ws_size >= XPROJ_BYTES * 3 + (1 << 20)) nks = 2;

  char* ws = (char*)d_ws;
  float* xproj = (float*)ws;                                  // 4 MB
  float* xpart = (float*)(ws + XPROJ_BYTES);                  // nks * 4 MB
  u64*   hmsg  = (u64*)(ws + XPROJ_BYTES * (1 + nks));        // 16 KB
  // hmsg deliberately NOT initialized: 0xAA poison tag never matches [1,256].

  const int kspan = K_IN / nks;
  xproj_gemm<<<dim3(TS / BN, G4 / BM, nks), 256, 0, stream>>>(frames, W_ih, xpart, kspan);
  xproj_reduce<<<dim3(TS * G4 / 4 / 256), 256, 0, stream>>>(xpart, nks, b_ih, b_hh, xproj);
  lstm_scan<<<dim3(NWG), 256, 0, stream>>>(W_hh, xproj, hmsg);
  fc_kernel<<<dim3(12288 / 64), 256, 0, stream>>>(fc_w, fc_b, hmsg, out);
}